// Round 9
// baseline (96.207 us; speedup 1.0000x reference)
//
#include <hip/hip_runtime.h>
#include <hip/hip_bf16.h>
#include <cstdint>
#include <cstddef>

#define N_NODES 8192
#define IN_DIM  128
#define OUT_DIM 64
#define LRELU_ALPHA 0.2f
#define S_SLICES 4
#define LOG2E 1.44269504f
#define NSTEP 16            // per-wave steps of 32 j over its 512-j window

using f32x16 = __attribute__((ext_vector_type(16))) float;
using bf16x8 = __attribute__((ext_vector_type(8))) short;

typedef const __attribute__((address_space(1))) int* gas_ptr;
typedef __attribute__((address_space(3))) int* las_ptr;

static __device__ __forceinline__ unsigned short f2bf(float x) {
    union { float f; unsigned u; } v; v.f = x;
    unsigned r = v.u + 0x7FFFu + ((v.u >> 16) & 1u);  // RNE (prep only)
    return (unsigned short)(r >> 16);
}

// ---------------------------------------------------------------------------
// K1: h = x@W ; svec = (h@a_src)*log2e ; dvec = (h@a_dst)*log2e ;
// hpack = bf16(h) in MFMA-B layout. Grid 1024 x 256thr, k-split over waves.
// ---------------------------------------------------------------------------
__global__ __launch_bounds__(256) void gat_prep(
    const float* __restrict__ x, const float* __restrict__ W,
    const float* __restrict__ a,
    float* __restrict__ svec, float* __restrict__ dvec,
    unsigned short* __restrict__ hpack)
{
    __shared__ float shA[4][8][64];
    const int tid = threadIdx.x;
    const int w   = tid >> 6;
    const int f   = tid & 63;
    const int i0  = blockIdx.x * 8;

    float acc[8];
#pragma unroll
    for (int r = 0; r < 8; ++r) acc[r] = 0.f;

    const int k0 = w * 32;
#pragma unroll 2
    for (int k = k0; k < k0 + 32; k += 4) {
        const float w0 = W[(k + 0) * OUT_DIM + f];
        const float w1 = W[(k + 1) * OUT_DIM + f];
        const float w2 = W[(k + 2) * OUT_DIM + f];
        const float w3 = W[(k + 3) * OUT_DIM + f];
#pragma unroll
        for (int r = 0; r < 8; ++r) {
            const float4 xv = *reinterpret_cast<const float4*>(
                x + (size_t)(i0 + r) * IN_DIM + k);
            acc[r] = fmaf(xv.x, w0, acc[r]);
            acc[r] = fmaf(xv.y, w1, acc[r]);
            acc[r] = fmaf(xv.z, w2, acc[r]);
            acc[r] = fmaf(xv.w, w3, acc[r]);
        }
    }
#pragma unroll
    for (int r = 0; r < 8; ++r) shA[w][r][f] = acc[r];
    __syncthreads();

    if (w == 0) {
        union { unsigned short us[8]; int4 v; } pk;
#pragma unroll
        for (int r = 0; r < 8; ++r) {
            const float hv = shA[0][r][f] + shA[1][r][f] + shA[2][r][f] + shA[3][r][f];
            pk.us[r] = f2bf(hv);
        }
        const int jb    = i0 >> 4;
        const int jhalf = (i0 >> 3) & 1;
        const int fb    = f >> 5;
        const int lidx  = (f & 31) + 32 * jhalf;
        *reinterpret_cast<int4*>(hpack + ((size_t)(jb * 2 + fb) * 64 + lidx) * 8) = pk.v;
    } else if (w == 1) {
        const float asrc = a[f];
#pragma unroll
        for (int r = 0; r < 8; ++r) {
            const float hv = shA[0][r][f] + shA[1][r][f] + shA[2][r][f] + shA[3][r][f];
            float sv = hv * asrc;
#pragma unroll
            for (int off = 32; off >= 1; off >>= 1) sv += __shfl_xor(sv, off);
            if (f == 0) svec[i0 + r] = sv * LOG2E;
        }
    } else if (w == 2) {
        const float adst = a[OUT_DIM + f];
#pragma unroll
        for (int r = 0; r < 8; ++r) {
            const float hv = shA[0][r][f] + shA[1][r][f] + shA[2][r][f] + shA[3][r][f];
            float dv = hv * adst;
#pragma unroll
            for (int off = 32; off >= 1; off >>= 1) dv += __shfl_xor(dv, off);
            if (f == 0) dvec[i0 + r] = dv * LOG2E;
        }
    }
}

// ---------------------------------------------------------------------------
// K2: WAVE-PRIVATE barrier-free streaming pass over adj.
// Grid (256 rb, 4 sl) x 256thr (4 waves). Each wave owns 32 rows x 512 j:
// 16 steps of 32 j. Per step: stage = 4 global_load_lds (1KB each = 8 rows x
// 128B contiguous, XOR-swizzled source) into a wave-private double buffer.
// Per-wave in-order VMEM queue is strictly [stage(s),plains(s),stage(s+1)]
// = 16 at the wait -> vmcnt(4) drains stage(s)+plains(s), keeps stage(s+1)
// in flight. NO s_barrier in the loop; buffer reuse guarded by lgkmcnt(0)
// (this wave's reads landed). Every group boundary fenced with an asm
// memory clobber (R7/R8 lesson: prologue load hoisting broke the count).
// Tail s=15: vmcnt(0); no clamped/dead loads anywhere.
// ---------------------------------------------------------------------------
__global__ __launch_bounds__(256, 4) void gat_main(
    const int* __restrict__ adj,
    const float* __restrict__ svec, const float* __restrict__ dvec,
    const unsigned short* __restrict__ hpack,
    float* __restrict__ pO, float* __restrict__ pDen)
{
    union SH {
        int tiles[4][2][1024];                                   // per-wave 2x4KB
        struct { float red[4][32][64]; float redden[4][32]; } r; // 33.3KB
    };
    __shared__ SH sh;

    const int tid = threadIdx.x;
    const int w   = tid >> 6;
    const int l   = tid & 63;
    const int rb  = blockIdx.x;
    const int sl  = blockIdx.y;
    const int row = l & 31;      // A-fragment row
    const int kh  = l >> 5;      // k-half
    const int i0  = rb * 32;
    const int jwv = sl * 2048 + w * 512;   // wave's private j-window

    const float s_i = svec[i0 + row];      // already * log2e
    asm volatile("" :: "v"(s_i));           // completed before staging begins
    const bf16x8* hp = reinterpret_cast<const bf16x8*>(hpack);

    const int lrow8 = l >> 3;   // staging: row within 8-row inst
    const int lu    = l & 7;    // staging: 16B unit within 128B row chunk

    // stage one 32x32 tile (4KB): 4 insts, each 8 rows x 128B contiguous.
    auto stage = [&](int buf, int ss) {
        const int jt = jwv + ss * 32;
#pragma unroll
        for (int q = 0; q < 4; ++q) {
            const int rq = q * 8 + lrow8;
            const int cu = lu ^ (rq & 7);           // XOR swizzle (source side)
            const int* gs = adj + (size_t)(i0 + rq) * N_NODES + jt + cu * 4;
            __builtin_amdgcn_global_load_lds((gas_ptr)gs,
                (las_ptr)&sh.tiles[w][buf][q * 256], 16, 0, 0);
        }
    };

    bf16x8 b00, b01, b10, b11, nb00, nb01, nb10, nb11;
    float4 dA0, dA1, dB0, dB1, nA0, nA1, nB0, nB1;

    // plains for step ss: 4 hpack B-frags + 4 dvec float4s (8 VMEM ops)
    auto loadP = [&](int ss,
                     bf16x8& x00, bf16x8& x01, bf16x8& x10, bf16x8& x11,
                     float4& y0, float4& y1, float4& y2, float4& y3) {
        const int jg = jwv + ss * 32;
        const int jb = jg >> 4;
        x00 = hp[(jb * 2 + 0) * 64 + l];
        x01 = hp[(jb * 2 + 1) * 64 + l];
        x10 = hp[(jb * 2 + 2) * 64 + l];   // = (jb+1)*2+0
        x11 = hp[(jb * 2 + 3) * 64 + l];   // = (jb+1)*2+1
        const int j0 = jg + kh * 8;
        y0 = *reinterpret_cast<const float4*>(dvec + j0);
        y1 = *reinterpret_cast<const float4*>(dvec + j0 + 4);
        y2 = *reinterpret_cast<const float4*>(dvec + j0 + 16);
        y3 = *reinterpret_cast<const float4*>(dvec + j0 + 20);
    };

    f32x16 acc0, acc1;
#pragma unroll
    for (int r = 0; r < 16; ++r) { acc0[r] = 0.f; acc1[r] = 0.f; }
    float den = 0.f;

    // prologue: stage(0) | plains(0) | stage(1) — order PINNED by clobbers
    stage(0, 0);
    asm volatile("" ::: "memory");
    loadP(0, b00, b01, b10, b11, dA0, dA1, dB0, dB1);
    asm volatile("" ::: "memory");
    stage(1, 1);
    asm volatile("" ::: "memory");

    const int swz  = row & 7;
    const int base = row * 32;

#pragma unroll 1
    for (int s = 0; s < NSTEP; ++s) {
        // queue entering: [stage(s)4, plains(s)8, stage(s+1)4] (s<15) -> 16
        //                 [stage(15)4, plains(15)8]            (s=15) -> 12
        if (s < NSTEP - 1) asm volatile("s_waitcnt vmcnt(4)" ::: "memory");
        else               asm volatile("s_waitcnt vmcnt(0)" ::: "memory");

        // ---- adj reads from this wave's tile (un-swizzle on read) ----
        const int* tb = &sh.tiles[w][s & 1][0];
        const int c0 = kh * 2;
        const int c1 = 4 + kh * 2;
        const int4 A00 = *reinterpret_cast<const int4*>(&tb[base + ((c0    ) ^ swz) * 4]);
        const int4 A01 = *reinterpret_cast<const int4*>(&tb[base + ((c0 + 1) ^ swz) * 4]);
        const int4 A10 = *reinterpret_cast<const int4*>(&tb[base + ((c1    ) ^ swz) * 4]);
        const int4 A11 = *reinterpret_cast<const int4*>(&tb[base + ((c1 + 1) ^ swz) * 4]);
        asm volatile("s_waitcnt lgkmcnt(0)" ::: "memory");   // reads in regs

        // ---- issue next plains, then next stage (order pinned) ----
        if (s + 1 < NSTEP) {
            loadP(s + 1, nb00, nb01, nb10, nb11, nA0, nA1, nB0, nB1);
            asm volatile("" ::: "memory");
        }
        if (s + 2 < NSTEP) {
            stage(s & 1, s + 2);     // overwrite safe: this wave's reads landed
            asm volatile("" ::: "memory");
        }

        // ---- compute (registers only) ----
        const float dd0[8] = {dA0.x, dA0.y, dA0.z, dA0.w, dA1.x, dA1.y, dA1.z, dA1.w};
        const int   ia0[8] = {A00.x, A00.y, A00.z, A00.w, A01.x, A01.y, A01.z, A01.w};
        const float dd1[8] = {dB0.x, dB0.y, dB0.z, dB0.w, dB1.x, dB1.y, dB1.z, dB1.w};
        const int   ia1[8] = {A10.x, A10.y, A10.z, A10.w, A11.x, A11.y, A11.z, A11.w};

        bf16x8 af0, af1;
#pragma unroll
        for (int e = 0; e < 8; ++e) {
            float ev = s_i + dd0[e];
            ev = fmaxf(ev, LRELU_ALPHA * ev);
            float pv = __builtin_amdgcn_exp2f(ev);
            pv = (ia0[e] > 0) ? pv : 0.f;
            union { float f; unsigned u; } pu; pu.f = pv;
            pu.u &= 0xFFFF0000u;
            den += pu.f;
            af0[e] = (short)(pu.u >> 16);
        }
#pragma unroll
        for (int e = 0; e < 8; ++e) {
            float ev = s_i + dd1[e];
            ev = fmaxf(ev, LRELU_ALPHA * ev);
            float pv = __builtin_amdgcn_exp2f(ev);
            pv = (ia1[e] > 0) ? pv : 0.f;
            union { float f; unsigned u; } pu; pu.f = pv;
            pu.u &= 0xFFFF0000u;
            den += pu.f;
            af1[e] = (short)(pu.u >> 16);
        }
        acc0 = __builtin_amdgcn_mfma_f32_32x32x16_bf16(af0, b00, acc0, 0, 0, 0);
        acc1 = __builtin_amdgcn_mfma_f32_32x32x16_bf16(af0, b01, acc1, 0, 0, 0);
        acc0 = __builtin_amdgcn_mfma_f32_32x32x16_bf16(af1, b10, acc0, 0, 0, 0);
        acc1 = __builtin_amdgcn_mfma_f32_32x32x16_bf16(af1, b11, acc1, 0, 0, 0);

        if (s + 1 < NSTEP) {   // rotate prefetched plains into current
            b00 = nb00; b01 = nb01; b10 = nb10; b11 = nb11;
            dA0 = nA0;  dA1 = nA1;  dB0 = nB0;  dB1 = nB1;
        }
    }

    __syncthreads();   // union becomes the reduction buffer

    // scatter acc via verified C/D layout: col=l&31, row=(r&3)+8*(r>>2)+4*kh
#pragma unroll
    for (int r = 0; r < 16; ++r) {
        const int orow = (r & 3) + 8 * (r >> 2) + 4 * kh;
        sh.r.red[w][orow][row]      = acc0[r];
        sh.r.red[w][orow][32 + row] = acc1[r];
    }
    const float dtot = den + __shfl_xor(den, 32);   // combine kh halves
    if (l < 32) sh.r.redden[w][l] = dtot;
    __syncthreads();

    float* po = pO + ((size_t)rb * S_SLICES + sl) * 2048;
    const float* rf = &sh.r.red[0][0][0];
    for (int e = tid; e < 2048; e += 256)
        po[e] = rf[e] + rf[2048 + e] + rf[4096 + e] + rf[6144 + e];
    if (tid < 32) {
        pDen[((size_t)rb * S_SLICES + sl) * 32 + tid] =
            sh.r.redden[0][tid] + sh.r.redden[1][tid] +
            sh.r.redden[2][tid] + sh.r.redden[3][tid];
    }
}

// ---------------------------------------------------------------------------
// K3: sum 4 slice partials, normalize, ELU, write fp32 output.
// ---------------------------------------------------------------------------
__global__ __launch_bounds__(256) void gat_final(
    const float* __restrict__ pO, const float* __restrict__ pDen,
    float* __restrict__ out)
{
    const int idx = blockIdx.x * 256 + threadIdx.x;
    const int i = idx >> 6;
    const int f = idx & 63;
    const int rb = i >> 5;
    const int r  = i & 31;
    const float* po = pO + (size_t)rb * S_SLICES * 2048 + r * 64 + f;
    const float v = po[0] + po[2048] + po[4096] + po[6144];
    const float* pd = pDen + (size_t)rb * S_SLICES * 32 + r;
    const float dsum = pd[0] + pd[32] + pd[64] + pd[96];
    const float o = v / dsum;
    out[idx] = (o > 0.f) ? o : expm1f(o);   // jax.nn.elu, alpha=1
}

extern "C" void kernel_launch(void* const* d_in, const int* in_sizes, int n_in,
                              void* d_out, int out_size, void* d_ws, size_t ws_size,
                              hipStream_t stream)
{
    const float* x   = (const float*)d_in[0];
    const int*   adj = (const int*)d_in[1];
    const float* W   = (const float*)d_in[2];
    const float* a   = (const float*)d_in[3];
    float* out = (float*)d_out;

    float* svec = (float*)d_ws;                                  // 8192 f32
    float* dvec = svec + N_NODES;                                // 8192 f32
    unsigned short* hpack = (unsigned short*)(dvec + N_NODES);   // 1 MB bf16
    float* pO = (float*)(hpack + (size_t)N_NODES * OUT_DIM);     // 8 MB
    float* pDen = pO + (size_t)256 * S_SLICES * 2048;            // 128 KB

    gat_prep<<<N_NODES / 8, 256, 0, stream>>>(x, W, a, svec, dvec, hpack);
    gat_main<<<dim3(256, S_SLICES), 256, 0, stream>>>(adj, svec, dvec, hpack, pO, pDen);
    gat_final<<<(N_NODES * OUT_DIM) / 256, 256, 0, stream>>>(pO, pDen, out);
}

// Round 10
// 92.053 us; speedup vs baseline: 1.0451x; 1.0451x over previous
//
#include <hip/hip_runtime.h>
#include <hip/hip_bf16.h>
#include <cstdint>
#include <cstddef>

#define N_NODES 8192
#define IN_DIM  128
#define OUT_DIM 64
#define LRELU_ALPHA 0.2f
#define S_SLICES 4
#define LOG2E 1.44269504f
#define NSUP 8              // supersteps of 256 j over the block's 2048-j window

using f32x16 = __attribute__((ext_vector_type(16))) float;
using bf16x8 = __attribute__((ext_vector_type(8))) short;
typedef unsigned long long u64;

static __device__ __forceinline__ unsigned short f2bf(float x) {
    union { float f; unsigned u; } v; v.f = x;
    unsigned r = v.u + 0x7FFFu + ((v.u >> 16) & 1u);  // RNE (prep only)
    return (unsigned short)(r >> 16);
}

// ---------------------------------------------------------------------------
// K1: h = x@W ; svec = (h@a_src)*log2e ; dvec = (h@a_dst)*log2e ;
// hpack = bf16(h) in MFMA-B layout. Grid 1024 x 256thr, k-split over waves.
// (unchanged from the verified R5 kernel)
// ---------------------------------------------------------------------------
__global__ __launch_bounds__(256) void gat_prep(
    const float* __restrict__ x, const float* __restrict__ W,
    const float* __restrict__ a,
    float* __restrict__ svec, float* __restrict__ dvec,
    unsigned short* __restrict__ hpack)
{
    __shared__ float shA[4][8][64];
    const int tid = threadIdx.x;
    const int w   = tid >> 6;
    const int f   = tid & 63;
    const int i0  = blockIdx.x * 8;

    float acc[8];
#pragma unroll
    for (int r = 0; r < 8; ++r) acc[r] = 0.f;

    const int k0 = w * 32;
#pragma unroll 2
    for (int k = k0; k < k0 + 32; k += 4) {
        const float w0 = W[(k + 0) * OUT_DIM + f];
        const float w1 = W[(k + 1) * OUT_DIM + f];
        const float w2 = W[(k + 2) * OUT_DIM + f];
        const float w3 = W[(k + 3) * OUT_DIM + f];
#pragma unroll
        for (int r = 0; r < 8; ++r) {
            const float4 xv = *reinterpret_cast<const float4*>(
                x + (size_t)(i0 + r) * IN_DIM + k);
            acc[r] = fmaf(xv.x, w0, acc[r]);
            acc[r] = fmaf(xv.y, w1, acc[r]);
            acc[r] = fmaf(xv.z, w2, acc[r]);
            acc[r] = fmaf(xv.w, w3, acc[r]);
        }
    }
#pragma unroll
    for (int r = 0; r < 8; ++r) shA[w][r][f] = acc[r];
    __syncthreads();

    if (w == 0) {
        union { unsigned short us[8]; int4 v; } pk;
#pragma unroll
        for (int r = 0; r < 8; ++r) {
            const float hv = shA[0][r][f] + shA[1][r][f] + shA[2][r][f] + shA[3][r][f];
            pk.us[r] = f2bf(hv);
        }
        const int jb    = i0 >> 4;
        const int jhalf = (i0 >> 3) & 1;
        const int fb    = f >> 5;
        const int lidx  = (f & 31) + 32 * jhalf;
        *reinterpret_cast<int4*>(hpack + ((size_t)(jb * 2 + fb) * 64 + lidx) * 8) = pk.v;
    } else if (w == 1) {
        const float asrc = a[f];
#pragma unroll
        for (int r = 0; r < 8; ++r) {
            const float hv = shA[0][r][f] + shA[1][r][f] + shA[2][r][f] + shA[3][r][f];
            float sv = hv * asrc;
#pragma unroll
            for (int off = 32; off >= 1; off >>= 1) sv += __shfl_xor(sv, off);
            if (f == 0) svec[i0 + r] = sv * LOG2E;
        }
    } else if (w == 2) {
        const float adst = a[OUT_DIM + f];
#pragma unroll
        for (int r = 0; r < 8; ++r) {
            const float hv = shA[0][r][f] + shA[1][r][f] + shA[2][r][f] + shA[3][r][f];
            float dv = hv * adst;
#pragma unroll
            for (int off = 32; off >= 1; off >>= 1) dv += __shfl_xor(dv, off);
            if (f == 0) dvec[i0 + r] = dv * LOG2E;
        }
    }
}

// ---------------------------------------------------------------------------
// K2: ballot-compress pass. Grid (256 rb, 4 sl) x 256thr (4 waves).
// Block = 32 rows x 2048 j, 8 supersteps of 256 j.
// PRODUCE (per wave, 8 rows): 32 coalesced dword loads (lane l -> j0s+g*64+l,
//   copy-kernel pattern), 32 __ballot -> u64 row-major bitmasks (bit l of
//   ballot IS adj[row][j0+l]), one coalesced 256B ds_write to the bit-plane.
// CONSUME (per wave, its fixed 64-j chunk): 1 ds_read_b64 of its rows' bits,
//   shift/mask extraction, exp2, 8 MFMA.
// NO global_load_lds, NO manual vmcnt: all waits compiler-generated against
// plain register loads. Barriers are raw s_barrier + lgkmcnt(0), so the
// in-flight adj loads for S+1 cross the barrier and land during compute(S).
// ---------------------------------------------------------------------------
__global__ __launch_bounds__(256, 4) void gat_main(
    const int* __restrict__ adj,
    const float* __restrict__ svec, const float* __restrict__ dvec,
    const unsigned short* __restrict__ hpack,
    float* __restrict__ pO, float* __restrict__ pDen)
{
    union SH {
        u64 bits[2][128];                                        // 2 planes x 1KB
        struct { float red[4][32][64]; float redden[4][32]; } r; // 33.3KB
    };
    __shared__ SH sh;

    const int tid = threadIdx.x;
    const int w   = tid >> 6;
    const int l   = tid & 63;
    const int rb  = blockIdx.x;
    const int sl  = blockIdx.y;
    const int row = l & 31;      // A-fragment row
    const int kh  = l >> 5;      // k-half
    const int i0  = rb * 32;
    const int jwin = sl * 2048;

    const float s_i = svec[i0 + row];      // already * log2e
    const bf16x8* hp = reinterpret_cast<const bf16x8*>(hpack);

    int av[32];   // producer's in-flight adj values (8 rows x 4 segs x lane)

    auto loads = [&](int S) {
        const int j0s = jwin + S * 256;
#pragma unroll
        for (int r8 = 0; r8 < 8; ++r8)
#pragma unroll
            for (int g = 0; g < 4; ++g)
                av[r8 * 4 + g] =
                    adj[(size_t)(i0 + w * 8 + r8) * N_NODES + j0s + g * 64 + l];
    };

    auto ballots_and_write = [&](int plane) {
        unsigned keepLo = 0, keepHi = 0;
#pragma unroll
        for (int m = 0; m < 32; ++m) {
            const u64 b = __ballot(av[m] != 0);
            if (l == m) { keepLo = (unsigned)b; keepHi = (unsigned)(b >> 32); }
        }
        if (l < 32) sh.bits[plane][w * 32 + l] = ((u64)keepHi << 32) | keepLo;
    };

    f32x16 acc0, acc1;
#pragma unroll
    for (int r = 0; r < 16; ++r) { acc0[r] = 0.f; acc1[r] = 0.f; }
    float den = 0.f;

    // prologue: produce superstep 0
    loads(0);
    ballots_and_write(0);
    asm volatile("s_waitcnt lgkmcnt(0)" ::: "memory");
    __builtin_amdgcn_s_barrier();
    asm volatile("" ::: "memory");

#pragma unroll 1
    for (int S = 0; S < NSUP; ++S) {
        const int plane = S & 1;
        const int j0s   = jwin + S * 256;

        // this wave's bits for its fixed 64-j chunk (word g == w)
        const u64 wv = sh.bits[plane][row * 4 + w];

        // issue next superstep's adj loads (plain, cross the barrier freely)
        if (S + 1 < NSUP) loads(S + 1);

        // ---- consume: 2 t-steps of 32 j ----
#pragma unroll
        for (int ti = 0; ti < 2; ++ti) {
            const unsigned b32 = ti ? (unsigned)(wv >> 32) : (unsigned)wv;
            const int jg = j0s + (w * 2 + ti) * 32;
            const int jb = jg >> 4;
            const bf16x8 b00 = hp[(jb * 2 + 0) * 64 + l];
            const bf16x8 b01 = hp[(jb * 2 + 1) * 64 + l];
            const bf16x8 b10 = hp[(jb * 2 + 2) * 64 + l];
            const bf16x8 b11 = hp[(jb * 2 + 3) * 64 + l];
            const int j0 = jg + kh * 8;
            const float4 dA0 = *reinterpret_cast<const float4*>(dvec + j0);
            const float4 dA1 = *reinterpret_cast<const float4*>(dvec + j0 + 4);
            const float4 dB0 = *reinterpret_cast<const float4*>(dvec + j0 + 16);
            const float4 dB1 = *reinterpret_cast<const float4*>(dvec + j0 + 20);

            const unsigned mq0 = b32 >> (kh * 8);        // bits for af0 (j = jg+kh*8+e)
            const unsigned mq1 = b32 >> (16 + kh * 8);   // bits for af1 (j = jg+16+kh*8+e)

            const float dd0[8] = {dA0.x, dA0.y, dA0.z, dA0.w, dA1.x, dA1.y, dA1.z, dA1.w};
            const float dd1[8] = {dB0.x, dB0.y, dB0.z, dB0.w, dB1.x, dB1.y, dB1.z, dB1.w};

            bf16x8 af0, af1;
#pragma unroll
            for (int e = 0; e < 8; ++e) {
                float ev = s_i + dd0[e];
                ev = fmaxf(ev, LRELU_ALPHA * ev);
                float pv = __builtin_amdgcn_exp2f(ev);
                pv = ((mq0 >> e) & 1u) ? pv : 0.f;
                union { float f; unsigned u; } pu; pu.f = pv;
                pu.u &= 0xFFFF0000u;
                den += pu.f;                   // denominator consistent w/ numerator
                af0[e] = (short)(pu.u >> 16);
            }
#pragma unroll
            for (int e = 0; e < 8; ++e) {
                float ev = s_i + dd1[e];
                ev = fmaxf(ev, LRELU_ALPHA * ev);
                float pv = __builtin_amdgcn_exp2f(ev);
                pv = ((mq1 >> e) & 1u) ? pv : 0.f;
                union { float f; unsigned u; } pu; pu.f = pv;
                pu.u &= 0xFFFF0000u;
                den += pu.f;
                af1[e] = (short)(pu.u >> 16);
            }
            acc0 = __builtin_amdgcn_mfma_f32_32x32x16_bf16(af0, b00, acc0, 0, 0, 0);
            acc1 = __builtin_amdgcn_mfma_f32_32x32x16_bf16(af0, b01, acc1, 0, 0, 0);
            acc0 = __builtin_amdgcn_mfma_f32_32x32x16_bf16(af1, b10, acc0, 0, 0, 0);
            acc1 = __builtin_amdgcn_mfma_f32_32x32x16_bf16(af1, b11, acc1, 0, 0, 0);
        }

        // ---- produce superstep S+1 into the other plane ----
        if (S + 1 < NSUP) ballots_and_write(plane ^ 1);

        asm volatile("s_waitcnt lgkmcnt(0)" ::: "memory");  // ds_writes visible,
        __builtin_amdgcn_s_barrier();                        // bits reads landed
        asm volatile("" ::: "memory");
    }

    // epilogue: union becomes the reduction buffer (barrier above protects it)
    // scatter acc via verified C/D layout: col=l&31, row=(r&3)+8*(r>>2)+4*kh
#pragma unroll
    for (int r = 0; r < 16; ++r) {
        const int orow = (r & 3) + 8 * (r >> 2) + 4 * kh;
        sh.r.red[w][orow][row]      = acc0[r];
        sh.r.red[w][orow][32 + row] = acc1[r];
    }
    const float dtot = den + __shfl_xor(den, 32);   // combine kh halves
    if (l < 32) sh.r.redden[w][l] = dtot;
    __syncthreads();

    float* po = pO + ((size_t)rb * S_SLICES + sl) * 2048;
    const float* rf = &sh.r.red[0][0][0];
    for (int e = tid; e < 2048; e += 256)
        po[e] = rf[e] + rf[2048 + e] + rf[4096 + e] + rf[6144 + e];
    if (tid < 32) {
        pDen[((size_t)rb * S_SLICES + sl) * 32 + tid] =
            sh.r.redden[0][tid] + sh.r.redden[1][tid] +
            sh.r.redden[2][tid] + sh.r.redden[3][tid];
    }
}

// ---------------------------------------------------------------------------
// K3: sum 4 slice partials, normalize, ELU, write fp32 output.
// ---------------------------------------------------------------------------
__global__ __launch_bounds__(256) void gat_final(
    const float* __restrict__ pO, const float* __restrict__ pDen,
    float* __restrict__ out)
{
    const int idx = blockIdx.x * 256 + threadIdx.x;
    const int i = idx >> 6;
    const int f = idx & 63;
    const int rb = i >> 5;
    const int r  = i & 31;
    const float* po = pO + (size_t)rb * S_SLICES * 2048 + r * 64 + f;
    const float v = po[0] + po[2048] + po[4096] + po[6144];
    const float* pd = pDen + (size_t)rb * S_SLICES * 32 + r;
    const float dsum = pd[0] + pd[32] + pd[64] + pd[96];
    const float o = v / dsum;
    out[idx] = (o > 0.f) ? o : expm1f(o);   // jax.nn.elu, alpha=1
}

extern "C" void kernel_launch(void* const* d_in, const int* in_sizes, int n_in,
                              void* d_out, int out_size, void* d_ws, size_t ws_size,
                              hipStream_t stream)
{
    const float* x   = (const float*)d_in[0];
    const int*   adj = (const int*)d_in[1];
    const float* W   = (const float*)d_in[2];
    const float* a   = (const float*)d_in[3];
    float* out = (float*)d_out;

    float* svec = (float*)d_ws;                                  // 8192 f32
    float* dvec = svec + N_NODES;                                // 8192 f32
    unsigned short* hpack = (unsigned short*)(dvec + N_NODES);   // 1 MB bf16
    float* pO = (float*)(hpack + (size_t)N_NODES * OUT_DIM);     // 8 MB
    float* pDen = pO + (size_t)256 * S_SLICES * 2048;            // 128 KB

    gat_prep<<<N_NODES / 8, 256, 0, stream>>>(x, W, a, svec, dvec, hpack);
    gat_main<<<dim3(256, S_SLICES), 256, 0, stream>>>(adj, svec, dvec, hpack, pO, pDen);
    gat_final<<<(N_NODES * OUT_DIM) / 256, 256, 0, stream>>>(pO, pDen, out);
}

// Round 11
// 76.937 us; speedup vs baseline: 1.2505x; 1.1965x over previous
//
#include <hip/hip_runtime.h>
#include <hip/hip_bf16.h>
#include <cstdint>
#include <cstddef>

#define N_NODES 8192
#define IN_DIM  128
#define OUT_DIM 64
#define LRELU_ALPHA 0.2f
#define S_SLICES 4
#define LOG2E 1.44269504f

using f32x16 = __attribute__((ext_vector_type(16))) float;
using bf16x8 = __attribute__((ext_vector_type(8))) short;
typedef unsigned long long u64;

static __device__ __forceinline__ unsigned short f2bf(float x) {
    union { float f; unsigned u; } v; v.f = x;
    unsigned r = v.u + 0x7FFFu + ((v.u >> 16) & 1u);  // RNE (prep only)
    return (unsigned short)(r >> 16);
}

// ---------------------------------------------------------------------------
// K1: h = x@W ; svec = (h@a_src)*log2e ; dvec = (h@a_dst)*log2e ;
// hpack = bf16(h) in MFMA-B layout. (verified, unchanged)
// ---------------------------------------------------------------------------
__global__ __launch_bounds__(256) void gat_prep(
    const float* __restrict__ x, const float* __restrict__ W,
    const float* __restrict__ a,
    float* __restrict__ svec, float* __restrict__ dvec,
    unsigned short* __restrict__ hpack)
{
    __shared__ float shA[4][8][64];
    const int tid = threadIdx.x;
    const int w   = tid >> 6;
    const int f   = tid & 63;
    const int i0  = blockIdx.x * 8;

    float acc[8];
#pragma unroll
    for (int r = 0; r < 8; ++r) acc[r] = 0.f;

    const int k0 = w * 32;
#pragma unroll 2
    for (int k = k0; k < k0 + 32; k += 4) {
        const float w0 = W[(k + 0) * OUT_DIM + f];
        const float w1 = W[(k + 1) * OUT_DIM + f];
        const float w2 = W[(k + 2) * OUT_DIM + f];
        const float w3 = W[(k + 3) * OUT_DIM + f];
#pragma unroll
        for (int r = 0; r < 8; ++r) {
            const float4 xv = *reinterpret_cast<const float4*>(
                x + (size_t)(i0 + r) * IN_DIM + k);
            acc[r] = fmaf(xv.x, w0, acc[r]);
            acc[r] = fmaf(xv.y, w1, acc[r]);
            acc[r] = fmaf(xv.z, w2, acc[r]);
            acc[r] = fmaf(xv.w, w3, acc[r]);
        }
    }
#pragma unroll
    for (int r = 0; r < 8; ++r) shA[w][r][f] = acc[r];
    __syncthreads();

    if (w == 0) {
        union { unsigned short us[8]; int4 v; } pk;
#pragma unroll
        for (int r = 0; r < 8; ++r) {
            const float hv = shA[0][r][f] + shA[1][r][f] + shA[2][r][f] + shA[3][r][f];
            pk.us[r] = f2bf(hv);
        }
        const int jb    = i0 >> 4;
        const int jhalf = (i0 >> 3) & 1;
        const int fb    = f >> 5;
        const int lidx  = (f & 31) + 32 * jhalf;
        *reinterpret_cast<int4*>(hpack + ((size_t)(jb * 2 + fb) * 64 + lidx) * 8) = pk.v;
    } else if (w == 1) {
        const float asrc = a[f];
#pragma unroll
        for (int r = 0; r < 8; ++r) {
            const float hv = shA[0][r][f] + shA[1][r][f] + shA[2][r][f] + shA[3][r][f];
            float sv = hv * asrc;
#pragma unroll
            for (int off = 32; off >= 1; off >>= 1) sv += __shfl_xor(sv, off);
            if (f == 0) svec[i0 + r] = sv * LOG2E;
        }
    } else if (w == 2) {
        const float adst = a[OUT_DIM + f];
#pragma unroll
        for (int r = 0; r < 8; ++r) {
            const float hv = shA[0][r][f] + shA[1][r][f] + shA[2][r][f] + shA[3][r][f];
            float dv = hv * adst;
#pragma unroll
            for (int off = 32; off >= 1; off >>= 1) dv += __shfl_xor(dv, off);
            if (f == 0) dvec[i0 + r] = dv * LOG2E;
        }
    }
}

// ---------------------------------------------------------------------------
// K2: wave-independent ballot-compress pass. Grid (256 rb, 4 sl) x 256thr.
// Block = 32 rows x 2048 j; wave w independently owns j-window w*512
// (8 chunks of 64 j, processed in (c + rb)&7 rotated order to spread
// concurrent j-phases machine-wide). Per chunk:
//   plains(c): 16 L2-hit loads  -> fence
//   adj(c+1):  32 coalesced 256B dword loads (copy-kernel pattern) -> fence
//   pack(c):   32 __ballot -> 2 VGPRs (32 rows x 64 bits)   [drains adj(c)]
//   consume:   2 shfl + bit-extract + exp2 + 8 MFMA          [drains plains(c)]
// NO barriers, NO LDS, NO manual vmcnt in the loop: all waits are
// compiler-generated, and in-order retirement only ever drains the oldest
// group (younger prefetches stay in flight). 256-VGPR budget (no spill).
// ---------------------------------------------------------------------------
__global__ __launch_bounds__(256, 2) void gat_main(
    const int* __restrict__ adj,
    const float* __restrict__ svec, const float* __restrict__ dvec,
    const unsigned short* __restrict__ hpack,
    float* __restrict__ pO, float* __restrict__ pDen)
{
    __shared__ struct { float red[4][32][64]; float redden[4][32]; } shr;

    const int tid = threadIdx.x;
    const int w   = tid >> 6;
    const int l   = tid & 63;
    const int rb  = blockIdx.x;
    const int sl  = blockIdx.y;
    const int row = l & 31;      // A-fragment row
    const int kh  = l >> 5;      // k-half
    const int i0  = rb * 32;
    const int jwv = sl * 2048 + w * 512;   // wave's private 512-j window
    const int rot = rb & 7;                // per-block chunk rotation

    const float s_i = svec[i0 + row];      // already * log2e
    const bf16x8* hp = reinterpret_cast<const bf16x8*>(hpack);

    struct Plains { bf16x8 b[2][4]; float4 d[2][4]; };

    auto j0of = [&](int c) { return jwv + (((c + rot) & 7) << 6); };

    auto loadAdj = [&](int (&av)[32], int c) {
        const int j0c = j0of(c);
#pragma unroll
        for (int m = 0; m < 32; ++m)
            av[m] = adj[(size_t)(i0 + m) * N_NODES + j0c + l];
    };

    auto loadPlains = [&](int c, Plains& P) {
        const int j0c = j0of(c);
#pragma unroll
        for (int ti = 0; ti < 2; ++ti) {
            const int jg = j0c + ti * 32;
            const int jb = jg >> 4;
#pragma unroll
            for (int q = 0; q < 4; ++q) P.b[ti][q] = hp[(jb * 2 + q) * 64 + l];
            const int j0 = jg + kh * 8;
            P.d[ti][0] = *reinterpret_cast<const float4*>(dvec + j0);
            P.d[ti][1] = *reinterpret_cast<const float4*>(dvec + j0 + 4);
            P.d[ti][2] = *reinterpret_cast<const float4*>(dvec + j0 + 16);
            P.d[ti][3] = *reinterpret_cast<const float4*>(dvec + j0 + 20);
        }
    };

    auto pack = [&](const int (&av)[32], unsigned& kLo, unsigned& kHi) {
        kLo = 0u; kHi = 0u;
#pragma unroll
        for (int m = 0; m < 32; ++m) {
            const u64 b = __ballot(av[m] != 0);
            if (l == m) { kLo = (unsigned)b; kHi = (unsigned)(b >> 32); }
        }
    };

    f32x16 acc0, acc1;
#pragma unroll
    for (int r = 0; r < 16; ++r) { acc0[r] = 0.f; acc1[r] = 0.f; }
    float den = 0.f;

    auto consume = [&](unsigned kLo, unsigned kHi, const Plains& P) {
        const unsigned lo32 = (unsigned)__shfl((int)kLo, row);
        const unsigned hi32 = (unsigned)__shfl((int)kHi, row);
#pragma unroll
        for (int ti = 0; ti < 2; ++ti) {
            const unsigned b32 = ti ? hi32 : lo32;
            const unsigned mq0 = b32 >> (kh * 8);          // j = jg + kh*8 + e
            const unsigned mq1 = b32 >> (16 + kh * 8);     // j = jg + 16 + kh*8 + e
            const float dd0[8] = {P.d[ti][0].x, P.d[ti][0].y, P.d[ti][0].z, P.d[ti][0].w,
                                  P.d[ti][1].x, P.d[ti][1].y, P.d[ti][1].z, P.d[ti][1].w};
            const float dd1[8] = {P.d[ti][2].x, P.d[ti][2].y, P.d[ti][2].z, P.d[ti][2].w,
                                  P.d[ti][3].x, P.d[ti][3].y, P.d[ti][3].z, P.d[ti][3].w};
            bf16x8 af0, af1;
#pragma unroll
            for (int e = 0; e < 8; ++e) {
                float ev = s_i + dd0[e];
                ev = fmaxf(ev, LRELU_ALPHA * ev);
                float pv = __builtin_amdgcn_exp2f(ev);
                pv = ((mq0 >> e) & 1u) ? pv : 0.f;
                union { float f; unsigned u; } pu; pu.f = pv;
                pu.u &= 0xFFFF0000u;
                den += pu.f;                 // denominator consistent w/ numerator
                af0[e] = (short)(pu.u >> 16);
            }
#pragma unroll
            for (int e = 0; e < 8; ++e) {
                float ev = s_i + dd1[e];
                ev = fmaxf(ev, LRELU_ALPHA * ev);
                float pv = __builtin_amdgcn_exp2f(ev);
                pv = ((mq1 >> e) & 1u) ? pv : 0.f;
                union { float f; unsigned u; } pu; pu.f = pv;
                pu.u &= 0xFFFF0000u;
                den += pu.f;
                af1[e] = (short)(pu.u >> 16);
            }
            acc0 = __builtin_amdgcn_mfma_f32_32x32x16_bf16(af0, P.b[ti][0], acc0, 0, 0, 0);
            acc1 = __builtin_amdgcn_mfma_f32_32x32x16_bf16(af0, P.b[ti][1], acc1, 0, 0, 0);
            acc0 = __builtin_amdgcn_mfma_f32_32x32x16_bf16(af1, P.b[ti][2], acc0, 0, 0, 0);
            acc1 = __builtin_amdgcn_mfma_f32_32x32x16_bf16(af1, P.b[ti][3], acc1, 0, 0, 0);
        }
    };

    int avA[32], avB[32];
    Plains P, Q;
    unsigned kLo, kHi;

    loadAdj(avA, 0);
    asm volatile("" ::: "memory");

#pragma unroll 1
    for (int c = 0; c < 8; c += 2) {
        // ---- chunk c (avA) ----
        loadPlains(c, P);
        asm volatile("" ::: "memory");
        loadAdj(avB, c + 1);                 // c+1 <= 7 always
        asm volatile("" ::: "memory");
        pack(avA, kLo, kHi);                 // drains avA(c) only (oldest)
        consume(kLo, kHi, P);                // drains plains(c); avB in flight
        // ---- chunk c+1 (avB) ----
        loadPlains(c + 1, Q);
        asm volatile("" ::: "memory");
        if (c + 2 < 8) {
            loadAdj(avA, c + 2);
            asm volatile("" ::: "memory");
        }
        pack(avB, kLo, kHi);                 // drains avB(c+1) only
        consume(kLo, kHi, Q);
    }

    // ---- epilogue: verified C/D layout scatter + 4-wave reduce ----
    __syncthreads();
#pragma unroll
    for (int r = 0; r < 16; ++r) {
        const int orow = (r & 3) + 8 * (r >> 2) + 4 * kh;
        shr.red[w][orow][row]      = acc0[r];
        shr.red[w][orow][32 + row] = acc1[r];
    }
    const float dtot = den + __shfl_xor(den, 32);   // combine kh halves
    if (l < 32) shr.redden[w][l] = dtot;
    __syncthreads();

    float* po = pO + ((size_t)rb * S_SLICES + sl) * 2048;
    const float* rf = &shr.red[0][0][0];
    for (int e = tid; e < 2048; e += 256)
        po[e] = rf[e] + rf[2048 + e] + rf[4096 + e] + rf[6144 + e];
    if (tid < 32) {
        pDen[((size_t)rb * S_SLICES + sl) * 32 + tid] =
            shr.redden[0][tid] + shr.redden[1][tid] +
            shr.redden[2][tid] + shr.redden[3][tid];
    }
}

// ---------------------------------------------------------------------------
// K3: sum 4 slice partials, normalize, ELU, write fp32 output. (verified)
// ---------------------------------------------------------------------------
__global__ __launch_bounds__(256) void gat_final(
    const float* __restrict__ pO, const float* __restrict__ pDen,
    float* __restrict__ out)
{
    const int idx = blockIdx.x * 256 + threadIdx.x;
    const int i = idx >> 6;
    const int f = idx & 63;
    const int rb = i >> 5;
    const int r  = i & 31;
    const float* po = pO + (size_t)rb * S_SLICES * 2048 + r * 64 + f;
    const float v = po[0] + po[2048] + po[4096] + po[6144];
    const float* pd = pDen + (size_t)rb * S_SLICES * 32 + r;
    const float dsum = pd[0] + pd[32] + pd[64] + pd[96];
    const float o = v / dsum;
    out[idx] = (o > 0.f) ? o : expm1f(o);   // jax.nn.elu, alpha=1
}

extern "C" void kernel_launch(void* const* d_in, const int* in_sizes, int n_in,
                              void* d_out, int out_size, void* d_ws, size_t ws_size,
                              hipStream_t stream)
{
    const float* x   = (const float*)d_in[0];
    const int*   adj = (const int*)d_in[1];
    const float* W   = (const float*)d_in[2];
    const float* a   = (const float*)d_in[3];
    float* out = (float*)d_out;

    float* svec = (float*)d_ws;                                  // 8192 f32
    float* dvec = svec + N_NODES;                                // 8192 f32
    unsigned short* hpack = (unsigned short*)(dvec + N_NODES);   // 1 MB bf16
    float* pO = (float*)(hpack + (size_t)N_NODES * OUT_DIM);     // 8 MB
    float* pDen = pO + (size_t)256 * S_SLICES * 2048;            // 128 KB

    gat_prep<<<N_NODES / 8, 256, 0, stream>>>(x, W, a, svec, dvec, hpack);
    gat_main<<<dim3(256, S_SLICES), 256, 0, stream>>>(adj, svec, dvec, hpack, pO, pDen);
    gat_final<<<(N_NODES * OUT_DIM) / 256, 256, 0, stream>>>(pO, pDen, out);
}